// Round 17
// baseline (199.789 us; speedup 1.0000x reference)
//
#include <hip/hip_runtime.h>
#include <hip/hip_bf16.h>
#include <math.h>

// Problem constants
#define BGR 8        // graphs
#define PP 4096      // points per graph
#define NPTS 32768   // B*P
#define KNN 20
#define LCOV 10
#define FF 32
#define KS 5
#define NCLS 40
#define NGROUP 24    // 3*B, rows of ys
#define GROUPLEN 131072  // P*F flat elements per group

// KNN tiling: 256 blocks x 1024 threads; thread = (eighth 0..7, pt 0..127)
#define SPLIT 8
#define CHUNK (PP / SPLIT)        // 512 candidates per thread
#define PTSBLK 128                // points per block
#define KTHR 1024
#define NSLOT (KNN + 1)           // 21-slot network (self-point absorbable)
#define MPAD NSLOT                // merge-list stride 21: gcd(21,32)=1
#define SENT 0xFFFFFFFFu
#define SCELLS 4096
#define SCAP 12                   // LDS scratch slots per lane
#define KBLKS 256                 // knn blocks = BN-partial rows

// ---------------------------------------------------------------------------
// R31 vs R30 (187.6us best; knn 107.9 w/ fused spline): two residual levers.
//  (a) Wsp -> LDS for the fused node phase: 640 dependent gathers/thread
//      were L1-served (~180cy); the 64KB coord arena is DEAD after phase 1,
//      so stage Wsp (16KB) there (4 loads/thread) and gather from LDS.
//      Same values -> bit-identical node. Predicted knn -3..-6us.
//  (b) fuse stats into ys (drop stats_kernel launch): each ys block
//      redundantly reduces sums_part[256][64] — the R29 null proved this
//      redundant-reduce is L2-served and ~free; saves one launch + gap.
// absmax note: R30's 0.0313 came from the BN-partial reduce order change;
// this round touches no arithmetic. Pre-committed: total >= 187 => declare
// ROOFLINE next round (fixed ~70us overhead + noise-band knn).
// ---------------------------------------------------------------------------
__device__ inline unsigned umn(unsigned a, unsigned b) { return a < b ? a : b; }
__device__ inline unsigned umx(unsigned a, unsigned b) { return a > b ? a : b; }

__device__ inline void mat3vec(const float M[9], const float v[3], float w[3]) {
    w[0] = M[0] * v[0] + M[1] * v[1] + M[2] * v[2];
    w[1] = M[3] * v[0] + M[4] * v[1] + M[5] * v[2];
    w[2] = M[6] * v[0] + M[7] * v[1] + M[8] * v[2];
}

__device__ inline float pi3(const float M[9], float v[3]) {
    v[0] = v[1] = v[2] = 0.57735026918962576f;  // 3^-0.5 as f32
#pragma unroll
    for (int it = 0; it < 5; ++it) {
        float w[3];
        mat3vec(M, v, w);
        float nrm = sqrtf(w[0] * w[0] + w[1] * w[1] + w[2] * w[2]) + 1e-12f;
        v[0] = w[0] / nrm;
        v[1] = w[1] / nrm;
        v[2] = w[2] / nrm;
    }
    float w[3];
    mat3vec(M, v, w);
    return v[0] * w[0] + v[1] * w[1] + v[2] * w[2];
}

__global__ __launch_bounds__(KTHR, 4) void knn_kernel(
    const float* __restrict__ pos, const float* __restrict__ Wsp,
    const float* __restrict__ root, const float* __restrict__ bias,
    float* __restrict__ node, float* __restrict__ sums_part,
    float* __restrict__ v3out) {
    __shared__ float smem[4 * PP];           // 64 KB arena
    __shared__ unsigned short mOrig[PP];     // Morton slot -> original local idx
    __shared__ unsigned samp[PTSBLK * 24];   // 12 KB: seed keys | R rows | BN red
    __shared__ float Tseed[PTSBLK];
    __shared__ unsigned scr[KTHR / 64][SCAP][64];  // 48 KB: accepts | w' overlay
    float* tx = smem;                // scan: -2x (ORIGINAL order) | merge: mk
    float* ty = smem + PP;
    float* tz = smem + 2 * PP;
    float* tw = smem + 3 * PP;       // |q|^2 (dead after scan)
    unsigned short* lnbr = (unsigned short*)(smem + 3 * PP + 2816);

    int b = blockIdx.x >> 5;          // 32 blocks per graph
    int blkInGraph = blockIdx.x & 31;
    const float* gp = pos + (size_t)b * PP * 3;
    int tid = threadIdx.x;
    int lane = tid & 63;
    int wid = tid >> 6;

    // ---- Phase A: Morton-cell counting sort (per-block, overlays arena) ----
    {
        unsigned* cnt = (unsigned*)smem;                         // words 0..4095
        unsigned short* cellOf = (unsigned short*)(smem + 4096); // words 4096..6143
        unsigned* tsum = (unsigned*)(smem + 6144);               // words 6144..7167
        for (int i = tid; i < SCELLS; i += KTHR) cnt[i] = 0u;
        __syncthreads();
        for (int i = tid; i < PP; i += KTHR) {
            float x = gp[i * 3 + 0];
            float y = gp[i * 3 + 1];
            float z = gp[i * 3 + 2];
            int cx = min(max((int)floorf((x + 4.0f) * 2.0f), 0), 15);
            int cy = min(max((int)floorf((y + 4.0f) * 2.0f), 0), 15);
            int cz = min(max((int)floorf((z + 4.0f) * 2.0f), 0), 15);
            unsigned m = 0;
#pragma unroll
            for (int bb = 0; bb < 4; ++bb)
                m |= (((unsigned)(cx >> bb) & 1u) << (3 * bb + 2)) |
                     (((unsigned)(cy >> bb) & 1u) << (3 * bb + 1)) |
                     (((unsigned)(cz >> bb) & 1u) << (3 * bb + 0));
            cellOf[i] = (unsigned short)m;
            atomicAdd(&cnt[m], 1u);
        }
        __syncthreads();
        unsigned c0 = cnt[4 * tid + 0];
        unsigned c1 = cnt[4 * tid + 1];
        unsigned c2 = cnt[4 * tid + 2];
        unsigned c3 = cnt[4 * tid + 3];
        unsigned local = c0 + c1 + c2 + c3;
        tsum[tid] = local;
        __syncthreads();
        for (int off = 1; off < 1024; off <<= 1) {
            unsigned v = (tid >= off) ? tsum[tid - off] : 0u;
            __syncthreads();
            tsum[tid] += v;
            __syncthreads();
        }
        unsigned base = tsum[tid] - local;   // exclusive prefix
        cnt[4 * tid + 0] = base;
        cnt[4 * tid + 1] = base + c0;
        cnt[4 * tid + 2] = base + c0 + c1;
        cnt[4 * tid + 3] = base + c0 + c1 + c2;
        __syncthreads();
        for (int i = tid; i < PP; i += KTHR) {
            unsigned dst = atomicAdd(&cnt[cellOf[i]], 1u);
            mOrig[dst] = (unsigned short)i;
        }
    }
    __syncthreads();

    // ---- Phase B: stage scan arrays in ORIGINAL order ----
    for (int i = tid; i < PP; i += KTHR) {
        float x = gp[i * 3 + 0];
        float y = gp[i * 3 + 1];
        float z = gp[i * 3 + 2];
        tx[i] = -2.0f * x;
        ty[i] = -2.0f * y;
        tz[i] = -2.0f * z;
        tw[i] = x * x + y * y + z * z;
    }
    __syncthreads();

    int eighth = tid >> 7;                // 0..7 (wave-uniform)
    int pt = tid & (PTSBLK - 1);          // 0..127
    int qSlot = blkInGraph * PTSBLK + pt; // query's Morton slot in graph
    int li = mOrig[qSlot];                // ORIGINAL local point index
    float px = -0.5f * tx[li];
    float py = -0.5f * ty[li];
    float pz = -0.5f * tz[li];
    float p2 = tw[li];
    int jbeg = eighth * CHUNK;

    // ---- seed: top-3 of 32 chunks x 4 consecutive slots (float4 loads) ----
    {
        unsigned s0 = SENT, s1 = SENT, s2 = SENT;
#pragma unroll 4
        for (int c = 0; c < 32; ++c) {
            int base = jbeg + c * 16;     // 4-aligned; max base+3 = jbeg+499
            float4 xv = *(const float4*)(tx + base);
            float4 yv = *(const float4*)(ty + base);
            float4 zv = *(const float4*)(tz + base);
            float4 wv = *(const float4*)(tw + base);
            float xa[4] = {xv.x, xv.y, xv.z, xv.w};
            float ya[4] = {yv.x, yv.y, yv.z, yv.w};
            float za[4] = {zv.x, zv.y, zv.z, zv.w};
            float wa[4] = {wv.x, wv.y, wv.z, wv.w};
#pragma unroll
            for (int u = 0; u < 4; ++u) {
                float dh = fmaf(px, xa[u], fmaf(py, ya[u], fmaf(pz, za[u], wa[u])));
                float d = fmaxf(dh + p2, 0.0f);
                unsigned key = (__float_as_uint(d) & 0xFFFFF000u)
                               | (unsigned)(base + u);
                if (base + u == li) key = SENT;   // self excluded
                unsigned t0 = umn(key, s0); key = umx(key, s0); s0 = t0;
                t0 = umn(key, s1); key = umx(key, s1); s1 = t0;
                s2 = umn(key, s2);
            }
        }
        unsigned* sdst = &samp[pt * 24 + eighth * 3];
        sdst[0] = s0; sdst[1] = s1; sdst[2] = s2;
    }
    __syncthreads();
    if (tid < PTSBLK) {
        // T = 21st smallest of 24 = 4th largest; +2 trunc-ulps headroom.
        unsigned g0 = 0, g1 = 0, g2 = 0, g3 = 0;
        const unsigned* ss = &samp[tid * 24];
#pragma unroll
        for (int i = 0; i < 24; ++i) {
            unsigned k = ss[i], a;
            a = umx(k, g0); k = umn(k, g0); g0 = a;
            a = umx(k, g1); k = umn(k, g1); g1 = a;
            a = umx(k, g2); k = umn(k, g2); g2 = a;
            g3 = umx(k, g3);
        }
        Tseed[tid] = __uint_as_float((g3 & 0xFFFFF000u) + 0x2000u);
    }
    __syncthreads();
    float seed_hat = Tseed[pt] - p2;

    unsigned bd[NSLOT];
#pragma unroll
    for (int k = 0; k < NSLOT; k++) bd[k] = SENT;
    float worst_hat = seed_hat;

    unsigned* scrW = &scr[wid][0][0];
    unsigned cnt = 0;

    auto drain = [&]() {
#pragma unroll
        for (int s = 0; s < SCAP; ++s) {
            if (!__any((int)cnt > s)) break;   // monotone fill 0..cnt-1
            unsigned k = (s < (int)cnt) ? scrW[s * 64 + lane] : SENT;
#pragma unroll
            for (int i = 0; i < NSLOT; i++) {
                unsigned lo = umn(k, bd[i]);   // v_min_u32
                k = umx(k, bd[i]);             // v_max_u32
                bd[i] = lo;
            }
        }
        cnt = 0;
        unsigned wb = bd[NSLOT - 1];
        float nw = (wb == SENT) ? INFINITY
                                : __uint_as_float(wb & 0xFFFFF000u) - p2;
        worst_hat = fminf(nw, seed_hat);
    };

    // ---- flat scan, ORIGINAL order, 8-wide (loads batched, 1 ballot/8) ----
    for (int jj = jbeg; jj < jbeg + CHUNK; jj += 8) {
        float4 xv0 = *(const float4*)(tx + jj);
        float4 yv0 = *(const float4*)(ty + jj);
        float4 zv0 = *(const float4*)(tz + jj);
        float4 wv0 = *(const float4*)(tw + jj);
        float4 xv1 = *(const float4*)(tx + jj + 4);
        float4 yv1 = *(const float4*)(ty + jj + 4);
        float4 zv1 = *(const float4*)(tz + jj + 4);
        float4 wv1 = *(const float4*)(tw + jj + 4);
        float xa[8] = {xv0.x, xv0.y, xv0.z, xv0.w, xv1.x, xv1.y, xv1.z, xv1.w};
        float ya[8] = {yv0.x, yv0.y, yv0.z, yv0.w, yv1.x, yv1.y, yv1.z, yv1.w};
        float za[8] = {zv0.x, zv0.y, zv0.z, zv0.w, zv1.x, zv1.y, zv1.z, zv1.w};
        float wa[8] = {wv0.x, wv0.y, wv0.z, wv0.w, wv1.x, wv1.y, wv1.z, wv1.w};
#pragma unroll
        for (int u = 0; u < 8; u++) {
            float dh = fmaf(px, xa[u], fmaf(py, ya[u], fmaf(pz, za[u], wa[u])));
            if (dh < worst_hat) {
                float d = fmaxf(dh + p2, 0.0f);
                scrW[cnt * 64 + lane] = (__float_as_uint(d) & 0xFFFFF000u)
                                        | (unsigned)(jj + u);
                cnt++;
            }
        }
        if (__any(cnt >= 4u)) drain();   // cap-12 safe: <=3 carry + 8/iter
    }
    drain();

    // ---- 8-way merge, two 64-point phases; emits LDS lnbr only ----
    __syncthreads();
    unsigned* mk = (unsigned*)smem;    // words 0..10751
    for (int h = 0; h < 2; h++) {
        if ((pt >> 6) == h) {
            int lpt = pt & 63;
#pragma unroll
            for (int k = 0; k < NSLOT; k++)
                mk[(eighth * 64 + lpt) * MPAD + k] = bd[k];
        }
        __syncthreads();
        if (tid < 64) {
            int p = tid;
            const unsigned* base = &mk[p * MPAD];
            int cur[SPLIT];
#pragma unroll
            for (int q = 0; q < SPLIT; q++) cur[q] = 0;
            int lpt2 = h * 64 + p;
#pragma unroll
            for (int t = 0; t < NSLOT; t++) {
                unsigned v[SPLIT];
#pragma unroll
                for (int q = 0; q < SPLIT; q++)
                    v[q] = base[q * 64 * MPAD + cur[q]];
                unsigned m = v[0];
#pragma unroll
                for (int q = 1; q < SPLIT; q++) m = umn(m, v[q]);
                if (t > 0) {
                    lnbr[lpt2 * KNN + (t - 1)] = (unsigned short)(m & 0xFFFu);
                }
#pragma unroll
                for (int q = 0; q < SPLIT; q++) cur[q] += (v[q] == m);
            }
        }
        __syncthreads();
    }

    // ---- re-stage RAW coords in ORIGINAL order (L2-hot) for the tail ----
    for (int i = tid; i < PP; i += KTHR) {
        tx[i] = gp[i * 3 + 0];
        ty[i] = gp[i * 3 + 1];
        tz[i] = gp[i * 3 + 2];
    }
    __syncthreads();

    // ---- eig tail: threads 0..127; R rows -> samp overlay (no Rbuf) ----
    if (tid < PTSBLK) {
        int lp = tid;
        int ng = mOrig[blkInGraph * PTSBLK + lp];   // ORIGINAL local idx
        int n = b * PP + ng;
        float qx = tx[ng], qy = ty[ng], qz = tz[ng];
        const unsigned short* ln = &lnbr[lp * KNN];

        float m00 = 0.f, m01 = 0.f, m02 = 0.f, m11 = 0.f, m12 = 0.f, m22 = 0.f;
#pragma unroll
        for (int k = 0; k < LCOV; k++) {
            int id = ln[k];
            float cx = tx[id] - qx;
            float cy = ty[id] - qy;
            float cz = tz[id] - qz;
            m00 += cx * cx; m01 += cx * cy; m02 += cx * cz;
            m11 += cy * cy; m12 += cy * cz; m22 += cz * cz;
        }
        float M[9] = {m00, m01, m02, m01, m11, m12, m02, m12, m22};

        float v1[3], v2[3], v3[3];
        float l1 = pi3(M, v1);
        float M2[9];
#pragma unroll
        for (int c = 0; c < 3; c++)
#pragma unroll
            for (int d = 0; d < 3; d++)
                M2[c * 3 + d] = M[c * 3 + d] - l1 * v1[c] * v1[d];
        pi3(M2, v2);
        v3[0] = v1[1] * v2[2] - v1[2] * v2[1];
        v3[1] = v1[2] * v2[0] - v1[0] * v2[2];
        v3[2] = v1[0] * v2[1] - v1[1] * v2[0];
        {
            float nrm = sqrtf(v3[0] * v3[0] + v3[1] * v3[1] + v3[2] * v3[2]) + 1e-12f;
            v3[0] /= nrm; v3[1] /= nrm; v3[2] /= nrm;
        }

        float ssum = 0.f, mx = 0.f;
#pragma unroll
        for (int k = 0; k < KNN; k++) {
            int id = ln[k];
            float cx = tx[id] - qx;
            float cy = ty[id] - qy;
            float cz = tz[id] - qz;
            float d0 = cx * v1[0] + cy * v1[1] + cz * v1[2];
            float d1 = cx * v2[0] + cy * v2[1] + cz * v2[2];
            float d2 = cx * v3[0] + cy * v3[1] + cz * v3[2];
            ssum += d2;
            mx = fmaxf(mx, fabsf(d0));
            mx = fmaxf(mx, fabsf(d1));
            mx = fmaxf(mx, fabsf(d2));
        }
        float sgn = (ssum > 0.f) ? 1.f : ((ssum < 0.f) ? -1.f : 0.f);

        float sc = 2.0f / mx;
        float* rrow = (float*)samp + lp * 12;
        rrow[0] = v1[0] * sc;  rrow[1] = v1[1] * sc;  rrow[2] = v1[2] * sc;
        rrow[3] = v2[0] * sc;  rrow[4] = v2[1] * sc;  rrow[5] = v2[2] * sc;
        float s2g = sgn * sc;
        rrow[6] = v3[0] * s2g; rrow[7] = v3[1] * s2g; rrow[8] = v3[2] * s2g;

        v3out[n * 3 + 0] = v3[0];
        v3out[n * 3 + 1] = v3[1];
        v3out[n * 3 + 2] = v3[2];
    }
    __syncthreads();

    // ---- fused spline, phase 1: packed w' for 128 pts x 20 k -> scr ----
    {
        float* wb = (float*)scr;                 // 40KB of 48KB (scan is done)
        const float* sampF = (const float*)samp; // R rows per pt
        for (int i = tid; i < PTSBLK * KNN; i += KTHR) {
            int lp = i / KNN;
            int k = i - lp * KNN;
            int ng = mOrig[blkInGraph * PTSBLK + lp];
            float qx = tx[ng], qy = ty[ng], qz = tz[ng];
            int id = lnbr[lp * KNN + k];
            float cxx = tx[id] - qx;
            float cyy = ty[id] - qy;
            float czz = tz[id] - qz;
            const float* r = &sampF[lp * 12];
            float v0 = fmaf(cxx, r[0], fmaf(cyy, r[1], fmaf(czz, r[2], 2.0f)));
            float v1 = fmaf(cxx, r[3], fmaf(cyy, r[4], fmaf(czz, r[5], 2.0f)));
            float v2 = fmaf(cxx, r[6], fmaf(cyy, r[7], fmaf(czz, r[8], 2.0f)));
            float f0 = floorf(v0), f1 = floorf(v1), f2 = floorf(v2);
            float fr0 = v0 - f0, fr1 = v1 - f1, fr2 = v2 - f2;
            int fi0 = (int)f0, fi1 = (int)f1, fi2 = (int)f2;
            float* wdst = &wb[i * 8];
#pragma unroll
            for (int s = 0; s < 8; s++) {
                int b0 = (s >> 2) & 1, b1 = (s >> 1) & 1, b2s = s & 1;
                int i0 = min(max(fi0 + b0, 0), KS - 1);
                int i1 = min(max(fi1 + b1, 0), KS - 1);
                int i2 = min(max(fi2 + b2s, 0), KS - 1);
                float w = (b0 ? fr0 : 1.f - fr0) * (b1 ? fr1 : 1.f - fr1) *
                          (b2s ? fr2 : 1.f - fr2);
                unsigned flat = (unsigned)((i0 * KS + i1) * KS + i2);
                wdst[s] = __uint_as_float((__float_as_uint(w) & ~127u) | flat);
            }
        }
    }
    __syncthreads();

    // ---- stage Wsp into the dead coord arena (16KB of 64KB) ----
    {
        float* sWsp = smem;                      // tx..tw dead after phase 1
        for (int i = tid; i < 125 * FF; i += KTHR) sWsp[i] = Wsp[i];
    }
    __syncthreads();

    // ---- fused spline, phase 2: node + BN partials (thread=(pt,f) x4) ----
    {
        const float* wb = (const float*)scr;
        const float* sWsp = smem;
        float bn1 = 0.f, bn2 = 0.f;
        int f = tid & 31;
#pragma unroll
        for (int it = 0; it < 4; ++it) {
            int lp = (tid >> 5) + 32 * it;     // 0..127
            const float* wrow = &wb[(lp * KNN) * 8];
            float acc = 0.f;
#pragma unroll
            for (int k = 0; k < KNN; k++) {
                float4 wa = *(const float4*)&wrow[k * 8];
                float4 wb4 = *(const float4*)&wrow[k * 8 + 4];
                float wv[8] = {wa.x, wa.y, wa.z, wa.w, wb4.x, wb4.y, wb4.z, wb4.w};
#pragma unroll
                for (int s = 0; s < 8; s++) {
                    unsigned u = __float_as_uint(wv[s]) & 127u;
                    acc = fmaf(wv[s], sWsp[u * FF + f], acc);
                }
            }
            float val = acc * (1.0f / KNN) + root[f] + bias[f];
            int ng = mOrig[blkInGraph * PTSBLK + lp];
            node[((size_t)b * PP + ng) * FF + f] = val;
            bn1 += val;
            bn2 += val * val;
        }
        float* redF = (float*)samp;            // 8KB of 12KB (R rows dead)
        redF[tid] = bn1;
        redF[1024 + tid] = bn2;
        __syncthreads();
        if (tid < 64) {
            int ff = tid & 31;
            int off = (tid >> 5) * 1024;       // 0 = sum, 1024 = sumsq
            float s = 0.f;
#pragma unroll
            for (int g = 0; g < 32; ++g) s += redF[off + (g << 5) + ff];
            sums_part[(size_t)blockIdx.x * 64 + tid] = s;
        }
    }
}

// ---------------------------------------------------------------------------
// Kernel 3: BN stats (fused, per-block redundant: L2-served, ~free per R29
// null) + BN apply + sigmoid + reduce to ys partials (YSPLIT=32).
// ---------------------------------------------------------------------------
#define YSPLIT 32
#define YCHUNK (GROUPLEN / YSPLIT)   // 4096
__global__ __launch_bounds__(256) void ys_kernel(
    const float* __restrict__ node, const float* __restrict__ v3,
    const float* __restrict__ sums_part, const float* __restrict__ gamma,
    const float* __restrict__ beta, float* __restrict__ ys_part) {
    __shared__ float stat4[256];
    __shared__ float stat[64];
    __shared__ float sa[FF], sb[FF];
    {   // reduce 256 partial rows: 4 quarters x 64 columns
        int col = threadIdx.x & 63;
        int q = threadIdx.x >> 6;
        float s = 0.f;
        for (int r = q * 64; r < (q + 1) * 64; ++r)
            s += sums_part[(size_t)r * 64 + col];
        stat4[threadIdx.x] = s;
    }
    __syncthreads();
    if (threadIdx.x < 64) {
        stat[threadIdx.x] = stat4[threadIdx.x] + stat4[64 + threadIdx.x] +
                            stat4[128 + threadIdx.x] + stat4[192 + threadIdx.x];
    }
    __syncthreads();
    if (threadIdx.x < FF) {
        int f = threadIdx.x;
        float mu = stat[f] * (1.0f / NPTS);
        float var = stat[FF + f] * (1.0f / NPTS) - mu * mu;
        float inv = 1.0f / sqrtf(var + 1e-5f);
        sa[f] = gamma[f] * inv;
        sb[f] = beta[f] - gamma[f] * inv * mu;
    }
    __syncthreads();

    int g = blockIdx.x >> 5;
    int sub = blockIdx.x & 31;
    int t0 = g * GROUPLEN + sub * YCHUNK + threadIdx.x;
    int n = t0 / 96;
    int r0 = t0 - n * 96;
    int rj[3], fj[3], cj[3], dj[3];
    rj[0] = r0;
    rj[1] = (r0 + 64) % 96;
    rj[2] = (r0 + 32) % 96;
#pragma unroll
    for (int j = 0; j < 3; j++) {
        fj[j] = rj[j] / 3;
        cj[j] = rj[j] - fj[j] * 3;
        dj[j] = (rj[j] >= 32) ? 3 : 2;
    }
    float Sa0 = sa[fj[0]], Sb0 = sb[fj[0]];
    float Sa1 = sa[fj[1]], Sb1 = sb[fj[1]];
    float Sa2 = sa[fj[2]], Sb2 = sb[fj[2]];
    int nf = n * FF;
    int n3 = n * 3;

    float acc = 0.f;
#pragma unroll 1
    for (int tr = 0; tr < 5; tr++) {
        {
            float xb = fmaf(Sa0, node[nf + fj[0]], Sb0);
            float val = xb * v3[n3 + cj[0]];
            acc += 1.0f / (1.0f + __expf(-val));
            nf += dj[0] * FF; n3 += dj[0] * 3;
        }
        {
            float xb = fmaf(Sa1, node[nf + fj[1]], Sb1);
            float val = xb * v3[n3 + cj[1]];
            acc += 1.0f / (1.0f + __expf(-val));
            nf += dj[1] * FF; n3 += dj[1] * 3;
        }
        {
            float xb = fmaf(Sa2, node[nf + fj[2]], Sb2);
            float val = xb * v3[n3 + cj[2]];
            acc += 1.0f / (1.0f + __expf(-val));
            nf += dj[2] * FF; n3 += dj[2] * 3;
        }
    }
    {
        float xb = fmaf(Sa0, node[nf + fj[0]], Sb0);
        float val = xb * v3[n3 + cj[0]];
        acc += 1.0f / (1.0f + __expf(-val));
    }

    __shared__ float red[256];
    red[threadIdx.x] = acc;
    __syncthreads();
    if (threadIdx.x < FF) {
        float s = 0.f;
        for (int t = threadIdx.x; t < 256; t += FF) s += red[t];
        ys_part[(sub * NGROUP + g) * FF + threadIdx.x] = s * (1.0f / PP);
    }
}

// ---------------------------------------------------------------------------
// Kernel 4: MLP head; sums the 32 ys partials while loading syr.
// ---------------------------------------------------------------------------
__global__ __launch_bounds__(256) void head_kernel(
    const float* __restrict__ ys_part, const float* __restrict__ W1,
    const float* __restrict__ b1, const float* __restrict__ W2,
    const float* __restrict__ b2, float* __restrict__ out) {
    int g = blockIdx.x;
    __shared__ float syr[FF];
    __shared__ float h[256];
    __shared__ float logits[NCLS];
    __shared__ float mstat[2];
    if (threadIdx.x < FF) {
        float s = 0.f;
#pragma unroll
        for (int sub = 0; sub < YSPLIT; sub++)
            s += ys_part[(sub * NGROUP + g) * FF + threadIdx.x];
        syr[threadIdx.x] = s;
    }
    __syncthreads();
    int j = threadIdx.x;
    float acc = b1[j];
#pragma unroll
    for (int f = 0; f < FF; f++) acc += syr[f] * W1[f * 256 + j];
    h[j] = acc > 0.f ? acc : expm1f(acc);
    __syncthreads();
    if (j < NCLS) {
        float l = b2[j];
        for (int q = 0; q < 256; q++) l += h[q] * W2[q * NCLS + j];
        logits[j] = l;
    }
    __syncthreads();
    if (j == 0) {
        float m = -INFINITY;
        for (int o = 0; o < NCLS; o++) m = fmaxf(m, logits[o]);
        float s = 0.f;
        for (int o = 0; o < NCLS; o++) s += expf(logits[o] - m);
        mstat[0] = m;
        mstat[1] = logf(s);
    }
    __syncthreads();
    if (j < NCLS) out[g * NCLS + j] = logits[j] - mstat[0] - mstat[1];
}

// ---------------------------------------------------------------------------
extern "C" void kernel_launch(void* const* d_in, const int* in_sizes, int n_in,
                              void* d_out, int out_size, void* d_ws, size_t ws_size,
                              hipStream_t stream) {
    const float* pos   = (const float*)d_in[0];
    const float* Wsp   = (const float*)d_in[1];
    const float* root  = (const float*)d_in[2];
    const float* bias  = (const float*)d_in[3];
    const float* gamma = (const float*)d_in[4];
    const float* beta  = (const float*)d_in[5];
    const float* W1    = (const float*)d_in[6];
    const float* b1    = (const float*)d_in[7];
    const float* W2    = (const float*)d_in[8];
    const float* b2    = (const float*)d_in[9];
    float* out = (float*)d_out;

    char* ws = (char*)d_ws;
    float* sums_part = (float*)(ws + 1310720);         // 256*64*4 = 65536
    float* ys_part   = (float*)(ws + 1835008);         // 32*24*32*4 = 98304
    float* node = (float*)(ws + 2621440);              // 32768*32*4 = 4194304
    float* v3   = (float*)(ws + 6815744);              // 32768*3*4  = 393216

    knn_kernel<<<KBLKS, KTHR, 0, stream>>>(pos, Wsp, root, bias, node,
                                           sums_part, v3);
    ys_kernel<<<NGROUP * YSPLIT, 256, 0, stream>>>(node, v3, sums_part, gamma,
                                                   beta, ys_part);
    head_kernel<<<NGROUP, 256, 0, stream>>>(ys_part, W1, b1, W2, b2, out);
}

// Round 18
// 183.323 us; speedup vs baseline: 1.0898x; 1.0898x over previous
//
#include <hip/hip_runtime.h>
#include <hip/hip_bf16.h>
#include <math.h>

// Problem constants
#define BGR 8        // graphs
#define PP 4096      // points per graph
#define NPTS 32768   // B*P
#define KNN 20
#define LCOV 10
#define FF 32
#define KS 5
#define NCLS 40
#define NGROUP 24    // 3*B, rows of ys
#define GROUPLEN 131072  // P*F flat elements per group

// KNN tiling: 256 blocks x 1024 threads; thread = (eighth 0..7, pt 0..127)
#define SPLIT 8
#define CHUNK (PP / SPLIT)        // 512 candidates per thread
#define PTSBLK 128                // points per block
#define KTHR 1024
#define NSLOT (KNN + 1)           // 21-slot network (self-point absorbable)
#define MPAD NSLOT                // merge-list stride 21: gcd(21,32)=1
#define SENT 0xFFFFFFFFu
#define SCELLS 4096
#define SCAP 12                   // LDS scratch slots per lane
#define KBLKS 256                 // knn blocks = BN-partial rows

// ---------------------------------------------------------------------------
// R32 vs R31 (199.8; knn 104.0): split verdict — (a) Wsp->LDS VALIDATED
// (knn 107.9->104.0); (b) stats-fused-into-ys REGRESSED (non-knn 80->96):
// R29's "redundant reduce is free" null was measured at 192 blocks; at 768
// blocks the per-block 64-row serial reduce + 2 barriers cost ~16us — the
// null didn't transfer across a 4x block-count change.
// R32 = R30 + (a) only: knn keeps LDS-staged Wsp; separate 64-block
// stats_kernel restored; slim ys reads sums_accum[64]. All byte-identical
// to verified code. Predicted total ~183-189. Session ends here: remaining
// spread = ±10us env noise + ~70us fixed harness overhead (invariant across
// 7 pipeline shapes); next round declares ROOFLINE.
// ---------------------------------------------------------------------------
__device__ inline unsigned umn(unsigned a, unsigned b) { return a < b ? a : b; }
__device__ inline unsigned umx(unsigned a, unsigned b) { return a > b ? a : b; }

__device__ inline void mat3vec(const float M[9], const float v[3], float w[3]) {
    w[0] = M[0] * v[0] + M[1] * v[1] + M[2] * v[2];
    w[1] = M[3] * v[0] + M[4] * v[1] + M[5] * v[2];
    w[2] = M[6] * v[0] + M[7] * v[1] + M[8] * v[2];
}

__device__ inline float pi3(const float M[9], float v[3]) {
    v[0] = v[1] = v[2] = 0.57735026918962576f;  // 3^-0.5 as f32
#pragma unroll
    for (int it = 0; it < 5; ++it) {
        float w[3];
        mat3vec(M, v, w);
        float nrm = sqrtf(w[0] * w[0] + w[1] * w[1] + w[2] * w[2]) + 1e-12f;
        v[0] = w[0] / nrm;
        v[1] = w[1] / nrm;
        v[2] = w[2] / nrm;
    }
    float w[3];
    mat3vec(M, v, w);
    return v[0] * w[0] + v[1] * w[1] + v[2] * w[2];
}

__global__ __launch_bounds__(KTHR, 4) void knn_kernel(
    const float* __restrict__ pos, const float* __restrict__ Wsp,
    const float* __restrict__ root, const float* __restrict__ bias,
    float* __restrict__ node, float* __restrict__ sums_part,
    float* __restrict__ v3out) {
    __shared__ float smem[4 * PP];           // 64 KB arena
    __shared__ unsigned short mOrig[PP];     // Morton slot -> original local idx
    __shared__ unsigned samp[PTSBLK * 24];   // 12 KB: seed keys | R rows | BN red
    __shared__ float Tseed[PTSBLK];
    __shared__ unsigned scr[KTHR / 64][SCAP][64];  // 48 KB: accepts | w' overlay
    float* tx = smem;                // scan: -2x (ORIGINAL order) | merge: mk
    float* ty = smem + PP;
    float* tz = smem + 2 * PP;
    float* tw = smem + 3 * PP;       // |q|^2 (dead after scan)
    unsigned short* lnbr = (unsigned short*)(smem + 3 * PP + 2816);

    int b = blockIdx.x >> 5;          // 32 blocks per graph
    int blkInGraph = blockIdx.x & 31;
    const float* gp = pos + (size_t)b * PP * 3;
    int tid = threadIdx.x;
    int lane = tid & 63;
    int wid = tid >> 6;

    // ---- Phase A: Morton-cell counting sort (per-block, overlays arena) ----
    {
        unsigned* cnt = (unsigned*)smem;                         // words 0..4095
        unsigned short* cellOf = (unsigned short*)(smem + 4096); // words 4096..6143
        unsigned* tsum = (unsigned*)(smem + 6144);               // words 6144..7167
        for (int i = tid; i < SCELLS; i += KTHR) cnt[i] = 0u;
        __syncthreads();
        for (int i = tid; i < PP; i += KTHR) {
            float x = gp[i * 3 + 0];
            float y = gp[i * 3 + 1];
            float z = gp[i * 3 + 2];
            int cx = min(max((int)floorf((x + 4.0f) * 2.0f), 0), 15);
            int cy = min(max((int)floorf((y + 4.0f) * 2.0f), 0), 15);
            int cz = min(max((int)floorf((z + 4.0f) * 2.0f), 0), 15);
            unsigned m = 0;
#pragma unroll
            for (int bb = 0; bb < 4; ++bb)
                m |= (((unsigned)(cx >> bb) & 1u) << (3 * bb + 2)) |
                     (((unsigned)(cy >> bb) & 1u) << (3 * bb + 1)) |
                     (((unsigned)(cz >> bb) & 1u) << (3 * bb + 0));
            cellOf[i] = (unsigned short)m;
            atomicAdd(&cnt[m], 1u);
        }
        __syncthreads();
        unsigned c0 = cnt[4 * tid + 0];
        unsigned c1 = cnt[4 * tid + 1];
        unsigned c2 = cnt[4 * tid + 2];
        unsigned c3 = cnt[4 * tid + 3];
        unsigned local = c0 + c1 + c2 + c3;
        tsum[tid] = local;
        __syncthreads();
        for (int off = 1; off < 1024; off <<= 1) {
            unsigned v = (tid >= off) ? tsum[tid - off] : 0u;
            __syncthreads();
            tsum[tid] += v;
            __syncthreads();
        }
        unsigned base = tsum[tid] - local;   // exclusive prefix
        cnt[4 * tid + 0] = base;
        cnt[4 * tid + 1] = base + c0;
        cnt[4 * tid + 2] = base + c0 + c1;
        cnt[4 * tid + 3] = base + c0 + c1 + c2;
        __syncthreads();
        for (int i = tid; i < PP; i += KTHR) {
            unsigned dst = atomicAdd(&cnt[cellOf[i]], 1u);
            mOrig[dst] = (unsigned short)i;
        }
    }
    __syncthreads();

    // ---- Phase B: stage scan arrays in ORIGINAL order ----
    for (int i = tid; i < PP; i += KTHR) {
        float x = gp[i * 3 + 0];
        float y = gp[i * 3 + 1];
        float z = gp[i * 3 + 2];
        tx[i] = -2.0f * x;
        ty[i] = -2.0f * y;
        tz[i] = -2.0f * z;
        tw[i] = x * x + y * y + z * z;
    }
    __syncthreads();

    int eighth = tid >> 7;                // 0..7 (wave-uniform)
    int pt = tid & (PTSBLK - 1);          // 0..127
    int qSlot = blkInGraph * PTSBLK + pt; // query's Morton slot in graph
    int li = mOrig[qSlot];                // ORIGINAL local point index
    float px = -0.5f * tx[li];
    float py = -0.5f * ty[li];
    float pz = -0.5f * tz[li];
    float p2 = tw[li];
    int jbeg = eighth * CHUNK;

    // ---- seed: top-3 of 32 chunks x 4 consecutive slots (float4 loads) ----
    {
        unsigned s0 = SENT, s1 = SENT, s2 = SENT;
#pragma unroll 4
        for (int c = 0; c < 32; ++c) {
            int base = jbeg + c * 16;     // 4-aligned; max base+3 = jbeg+499
            float4 xv = *(const float4*)(tx + base);
            float4 yv = *(const float4*)(ty + base);
            float4 zv = *(const float4*)(tz + base);
            float4 wv = *(const float4*)(tw + base);
            float xa[4] = {xv.x, xv.y, xv.z, xv.w};
            float ya[4] = {yv.x, yv.y, yv.z, yv.w};
            float za[4] = {zv.x, zv.y, zv.z, zv.w};
            float wa[4] = {wv.x, wv.y, wv.z, wv.w};
#pragma unroll
            for (int u = 0; u < 4; ++u) {
                float dh = fmaf(px, xa[u], fmaf(py, ya[u], fmaf(pz, za[u], wa[u])));
                float d = fmaxf(dh + p2, 0.0f);
                unsigned key = (__float_as_uint(d) & 0xFFFFF000u)
                               | (unsigned)(base + u);
                if (base + u == li) key = SENT;   // self excluded
                unsigned t0 = umn(key, s0); key = umx(key, s0); s0 = t0;
                t0 = umn(key, s1); key = umx(key, s1); s1 = t0;
                s2 = umn(key, s2);
            }
        }
        unsigned* sdst = &samp[pt * 24 + eighth * 3];
        sdst[0] = s0; sdst[1] = s1; sdst[2] = s2;
    }
    __syncthreads();
    if (tid < PTSBLK) {
        // T = 21st smallest of 24 = 4th largest; +2 trunc-ulps headroom.
        unsigned g0 = 0, g1 = 0, g2 = 0, g3 = 0;
        const unsigned* ss = &samp[tid * 24];
#pragma unroll
        for (int i = 0; i < 24; ++i) {
            unsigned k = ss[i], a;
            a = umx(k, g0); k = umn(k, g0); g0 = a;
            a = umx(k, g1); k = umn(k, g1); g1 = a;
            a = umx(k, g2); k = umn(k, g2); g2 = a;
            g3 = umx(k, g3);
        }
        Tseed[tid] = __uint_as_float((g3 & 0xFFFFF000u) + 0x2000u);
    }
    __syncthreads();
    float seed_hat = Tseed[pt] - p2;

    unsigned bd[NSLOT];
#pragma unroll
    for (int k = 0; k < NSLOT; k++) bd[k] = SENT;
    float worst_hat = seed_hat;

    unsigned* scrW = &scr[wid][0][0];
    unsigned cnt = 0;

    auto drain = [&]() {
#pragma unroll
        for (int s = 0; s < SCAP; ++s) {
            if (!__any((int)cnt > s)) break;   // monotone fill 0..cnt-1
            unsigned k = (s < (int)cnt) ? scrW[s * 64 + lane] : SENT;
#pragma unroll
            for (int i = 0; i < NSLOT; i++) {
                unsigned lo = umn(k, bd[i]);   // v_min_u32
                k = umx(k, bd[i]);             // v_max_u32
                bd[i] = lo;
            }
        }
        cnt = 0;
        unsigned wb = bd[NSLOT - 1];
        float nw = (wb == SENT) ? INFINITY
                                : __uint_as_float(wb & 0xFFFFF000u) - p2;
        worst_hat = fminf(nw, seed_hat);
    };

    // ---- flat scan, ORIGINAL order, 8-wide (loads batched, 1 ballot/8) ----
    for (int jj = jbeg; jj < jbeg + CHUNK; jj += 8) {
        float4 xv0 = *(const float4*)(tx + jj);
        float4 yv0 = *(const float4*)(ty + jj);
        float4 zv0 = *(const float4*)(tz + jj);
        float4 wv0 = *(const float4*)(tw + jj);
        float4 xv1 = *(const float4*)(tx + jj + 4);
        float4 yv1 = *(const float4*)(ty + jj + 4);
        float4 zv1 = *(const float4*)(tz + jj + 4);
        float4 wv1 = *(const float4*)(tw + jj + 4);
        float xa[8] = {xv0.x, xv0.y, xv0.z, xv0.w, xv1.x, xv1.y, xv1.z, xv1.w};
        float ya[8] = {yv0.x, yv0.y, yv0.z, yv0.w, yv1.x, yv1.y, yv1.z, yv1.w};
        float za[8] = {zv0.x, zv0.y, zv0.z, zv0.w, zv1.x, zv1.y, zv1.z, zv1.w};
        float wa[8] = {wv0.x, wv0.y, wv0.z, wv0.w, wv1.x, wv1.y, wv1.z, wv1.w};
#pragma unroll
        for (int u = 0; u < 8; u++) {
            float dh = fmaf(px, xa[u], fmaf(py, ya[u], fmaf(pz, za[u], wa[u])));
            if (dh < worst_hat) {
                float d = fmaxf(dh + p2, 0.0f);
                scrW[cnt * 64 + lane] = (__float_as_uint(d) & 0xFFFFF000u)
                                        | (unsigned)(jj + u);
                cnt++;
            }
        }
        if (__any(cnt >= 4u)) drain();   // cap-12 safe: <=3 carry + 8/iter
    }
    drain();

    // ---- 8-way merge, two 64-point phases; emits LDS lnbr only ----
    __syncthreads();
    unsigned* mk = (unsigned*)smem;    // words 0..10751
    for (int h = 0; h < 2; h++) {
        if ((pt >> 6) == h) {
            int lpt = pt & 63;
#pragma unroll
            for (int k = 0; k < NSLOT; k++)
                mk[(eighth * 64 + lpt) * MPAD + k] = bd[k];
        }
        __syncthreads();
        if (tid < 64) {
            int p = tid;
            const unsigned* base = &mk[p * MPAD];
            int cur[SPLIT];
#pragma unroll
            for (int q = 0; q < SPLIT; q++) cur[q] = 0;
            int lpt2 = h * 64 + p;
#pragma unroll
            for (int t = 0; t < NSLOT; t++) {
                unsigned v[SPLIT];
#pragma unroll
                for (int q = 0; q < SPLIT; q++)
                    v[q] = base[q * 64 * MPAD + cur[q]];
                unsigned m = v[0];
#pragma unroll
                for (int q = 1; q < SPLIT; q++) m = umn(m, v[q]);
                if (t > 0) {
                    lnbr[lpt2 * KNN + (t - 1)] = (unsigned short)(m & 0xFFFu);
                }
#pragma unroll
                for (int q = 0; q < SPLIT; q++) cur[q] += (v[q] == m);
            }
        }
        __syncthreads();
    }

    // ---- re-stage RAW coords in ORIGINAL order (L2-hot) for the tail ----
    for (int i = tid; i < PP; i += KTHR) {
        tx[i] = gp[i * 3 + 0];
        ty[i] = gp[i * 3 + 1];
        tz[i] = gp[i * 3 + 2];
    }
    __syncthreads();

    // ---- eig tail: threads 0..127; R rows -> samp overlay (no Rbuf) ----
    if (tid < PTSBLK) {
        int lp = tid;
        int ng = mOrig[blkInGraph * PTSBLK + lp];   // ORIGINAL local idx
        int n = b * PP + ng;
        float qx = tx[ng], qy = ty[ng], qz = tz[ng];
        const unsigned short* ln = &lnbr[lp * KNN];

        float m00 = 0.f, m01 = 0.f, m02 = 0.f, m11 = 0.f, m12 = 0.f, m22 = 0.f;
#pragma unroll
        for (int k = 0; k < LCOV; k++) {
            int id = ln[k];
            float cx = tx[id] - qx;
            float cy = ty[id] - qy;
            float cz = tz[id] - qz;
            m00 += cx * cx; m01 += cx * cy; m02 += cx * cz;
            m11 += cy * cy; m12 += cy * cz; m22 += cz * cz;
        }
        float M[9] = {m00, m01, m02, m01, m11, m12, m02, m12, m22};

        float v1[3], v2[3], v3[3];
        float l1 = pi3(M, v1);
        float M2[9];
#pragma unroll
        for (int c = 0; c < 3; c++)
#pragma unroll
            for (int d = 0; d < 3; d++)
                M2[c * 3 + d] = M[c * 3 + d] - l1 * v1[c] * v1[d];
        pi3(M2, v2);
        v3[0] = v1[1] * v2[2] - v1[2] * v2[1];
        v3[1] = v1[2] * v2[0] - v1[0] * v2[2];
        v3[2] = v1[0] * v2[1] - v1[1] * v2[0];
        {
            float nrm = sqrtf(v3[0] * v3[0] + v3[1] * v3[1] + v3[2] * v3[2]) + 1e-12f;
            v3[0] /= nrm; v3[1] /= nrm; v3[2] /= nrm;
        }

        float ssum = 0.f, mx = 0.f;
#pragma unroll
        for (int k = 0; k < KNN; k++) {
            int id = ln[k];
            float cx = tx[id] - qx;
            float cy = ty[id] - qy;
            float cz = tz[id] - qz;
            float d0 = cx * v1[0] + cy * v1[1] + cz * v1[2];
            float d1 = cx * v2[0] + cy * v2[1] + cz * v2[2];
            float d2 = cx * v3[0] + cy * v3[1] + cz * v3[2];
            ssum += d2;
            mx = fmaxf(mx, fabsf(d0));
            mx = fmaxf(mx, fabsf(d1));
            mx = fmaxf(mx, fabsf(d2));
        }
        float sgn = (ssum > 0.f) ? 1.f : ((ssum < 0.f) ? -1.f : 0.f);

        float sc = 2.0f / mx;
        float* rrow = (float*)samp + lp * 12;
        rrow[0] = v1[0] * sc;  rrow[1] = v1[1] * sc;  rrow[2] = v1[2] * sc;
        rrow[3] = v2[0] * sc;  rrow[4] = v2[1] * sc;  rrow[5] = v2[2] * sc;
        float s2g = sgn * sc;
        rrow[6] = v3[0] * s2g; rrow[7] = v3[1] * s2g; rrow[8] = v3[2] * s2g;

        v3out[n * 3 + 0] = v3[0];
        v3out[n * 3 + 1] = v3[1];
        v3out[n * 3 + 2] = v3[2];
    }
    __syncthreads();

    // ---- fused spline, phase 1: packed w' for 128 pts x 20 k -> scr ----
    {
        float* wb = (float*)scr;                 // 40KB of 48KB (scan is done)
        const float* sampF = (const float*)samp; // R rows per pt
        for (int i = tid; i < PTSBLK * KNN; i += KTHR) {
            int lp = i / KNN;
            int k = i - lp * KNN;
            int ng = mOrig[blkInGraph * PTSBLK + lp];
            float qx = tx[ng], qy = ty[ng], qz = tz[ng];
            int id = lnbr[lp * KNN + k];
            float cxx = tx[id] - qx;
            float cyy = ty[id] - qy;
            float czz = tz[id] - qz;
            const float* r = &sampF[lp * 12];
            float v0 = fmaf(cxx, r[0], fmaf(cyy, r[1], fmaf(czz, r[2], 2.0f)));
            float v1 = fmaf(cxx, r[3], fmaf(cyy, r[4], fmaf(czz, r[5], 2.0f)));
            float v2 = fmaf(cxx, r[6], fmaf(cyy, r[7], fmaf(czz, r[8], 2.0f)));
            float f0 = floorf(v0), f1 = floorf(v1), f2 = floorf(v2);
            float fr0 = v0 - f0, fr1 = v1 - f1, fr2 = v2 - f2;
            int fi0 = (int)f0, fi1 = (int)f1, fi2 = (int)f2;
            float* wdst = &wb[i * 8];
#pragma unroll
            for (int s = 0; s < 8; s++) {
                int b0 = (s >> 2) & 1, b1 = (s >> 1) & 1, b2s = s & 1;
                int i0 = min(max(fi0 + b0, 0), KS - 1);
                int i1 = min(max(fi1 + b1, 0), KS - 1);
                int i2 = min(max(fi2 + b2s, 0), KS - 1);
                float w = (b0 ? fr0 : 1.f - fr0) * (b1 ? fr1 : 1.f - fr1) *
                          (b2s ? fr2 : 1.f - fr2);
                unsigned flat = (unsigned)((i0 * KS + i1) * KS + i2);
                wdst[s] = __uint_as_float((__float_as_uint(w) & ~127u) | flat);
            }
        }
    }
    __syncthreads();

    // ---- stage Wsp into the dead coord arena (16KB of 64KB) ----
    {
        float* sWsp = smem;                      // tx..tw dead after phase 1
        for (int i = tid; i < 125 * FF; i += KTHR) sWsp[i] = Wsp[i];
    }
    __syncthreads();

    // ---- fused spline, phase 2: node + BN partials (thread=(pt,f) x4) ----
    {
        const float* wb = (const float*)scr;
        const float* sWsp = smem;
        float bn1 = 0.f, bn2 = 0.f;
        int f = tid & 31;
#pragma unroll
        for (int it = 0; it < 4; ++it) {
            int lp = (tid >> 5) + 32 * it;     // 0..127
            const float* wrow = &wb[(lp * KNN) * 8];
            float acc = 0.f;
#pragma unroll
            for (int k = 0; k < KNN; k++) {
                float4 wa = *(const float4*)&wrow[k * 8];
                float4 wb4 = *(const float4*)&wrow[k * 8 + 4];
                float wv[8] = {wa.x, wa.y, wa.z, wa.w, wb4.x, wb4.y, wb4.z, wb4.w};
#pragma unroll
                for (int s = 0; s < 8; s++) {
                    unsigned u = __float_as_uint(wv[s]) & 127u;
                    acc = fmaf(wv[s], sWsp[u * FF + f], acc);
                }
            }
            float val = acc * (1.0f / KNN) + root[f] + bias[f];
            int ng = mOrig[blkInGraph * PTSBLK + lp];
            node[((size_t)b * PP + ng) * FF + f] = val;
            bn1 += val;
            bn2 += val * val;
        }
        float* redF = (float*)samp;            // 8KB of 12KB (R rows dead)
        redF[tid] = bn1;
        redF[1024 + tid] = bn2;
        __syncthreads();
        if (tid < 64) {
            int ff = tid & 31;
            int off = (tid >> 5) * 1024;       // 0 = sum, 1024 = sumsq
            float s = 0.f;
#pragma unroll
            for (int g = 0; g < 32; ++g) s += redF[off + (g << 5) + ff];
            sums_part[(size_t)blockIdx.x * 64 + tid] = s;
        }
    }
}

// ---------------------------------------------------------------------------
// Kernel 2b: single-pass stats reduce — 64 blocks, one column each.
// ---------------------------------------------------------------------------
__global__ __launch_bounds__(256) void stats_kernel(
    const float* __restrict__ sums_part, float* __restrict__ sums_accum) {
    int c = blockIdx.x;              // 0..63
    __shared__ float red[256];
    float s = 0.f;
    for (int r = threadIdx.x; r < KBLKS; r += 256)
        s += sums_part[(size_t)r * 64 + c];
    red[threadIdx.x] = s;
    __syncthreads();
    for (int off = 128; off > 0; off >>= 1) {
        if (threadIdx.x < off) red[threadIdx.x] += red[threadIdx.x + off];
        __syncthreads();
    }
    if (threadIdx.x == 0) sums_accum[c] = red[0];
}

// ---------------------------------------------------------------------------
// Kernel 3: BN apply + sigmoid + reduce to ys partials (YSPLIT=32: 768
// blocks = 3 waves/SIMD; 16 elements/thread = 5 triples + 1).
// ---------------------------------------------------------------------------
#define YSPLIT 32
#define YCHUNK (GROUPLEN / YSPLIT)   // 4096
__global__ __launch_bounds__(256) void ys_kernel(
    const float* __restrict__ node, const float* __restrict__ v3,
    const float* __restrict__ sums_accum, const float* __restrict__ gamma,
    const float* __restrict__ beta, float* __restrict__ ys_part) {
    __shared__ float sa[FF], sb[FF];
    if (threadIdx.x < FF) {
        int f = threadIdx.x;
        float mu = sums_accum[f] * (1.0f / NPTS);
        float var = sums_accum[FF + f] * (1.0f / NPTS) - mu * mu;
        float inv = 1.0f / sqrtf(var + 1e-5f);
        sa[f] = gamma[f] * inv;
        sb[f] = beta[f] - gamma[f] * inv * mu;
    }
    __syncthreads();

    int g = blockIdx.x >> 5;
    int sub = blockIdx.x & 31;
    int t0 = g * GROUPLEN + sub * YCHUNK + threadIdx.x;
    int n = t0 / 96;
    int r0 = t0 - n * 96;
    int rj[3], fj[3], cj[3], dj[3];
    rj[0] = r0;
    rj[1] = (r0 + 64) % 96;
    rj[2] = (r0 + 32) % 96;
#pragma unroll
    for (int j = 0; j < 3; j++) {
        fj[j] = rj[j] / 3;
        cj[j] = rj[j] - fj[j] * 3;
        dj[j] = (rj[j] >= 32) ? 3 : 2;
    }
    float Sa0 = sa[fj[0]], Sb0 = sb[fj[0]];
    float Sa1 = sa[fj[1]], Sb1 = sb[fj[1]];
    float Sa2 = sa[fj[2]], Sb2 = sb[fj[2]];
    int nf = n * FF;
    int n3 = n * 3;

    float acc = 0.f;
#pragma unroll 1
    for (int tr = 0; tr < 5; tr++) {
        {
            float xb = fmaf(Sa0, node[nf + fj[0]], Sb0);
            float val = xb * v3[n3 + cj[0]];
            acc += 1.0f / (1.0f + __expf(-val));
            nf += dj[0] * FF; n3 += dj[0] * 3;
        }
        {
            float xb = fmaf(Sa1, node[nf + fj[1]], Sb1);
            float val = xb * v3[n3 + cj[1]];
            acc += 1.0f / (1.0f + __expf(-val));
            nf += dj[1] * FF; n3 += dj[1] * 3;
        }
        {
            float xb = fmaf(Sa2, node[nf + fj[2]], Sb2);
            float val = xb * v3[n3 + cj[2]];
            acc += 1.0f / (1.0f + __expf(-val));
            nf += dj[2] * FF; n3 += dj[2] * 3;
        }
    }
    {
        float xb = fmaf(Sa0, node[nf + fj[0]], Sb0);
        float val = xb * v3[n3 + cj[0]];
        acc += 1.0f / (1.0f + __expf(-val));
    }

    __shared__ float red[256];
    red[threadIdx.x] = acc;
    __syncthreads();
    if (threadIdx.x < FF) {
        float s = 0.f;
        for (int t = threadIdx.x; t < 256; t += FF) s += red[t];
        ys_part[(sub * NGROUP + g) * FF + threadIdx.x] = s * (1.0f / PP);
    }
}

// ---------------------------------------------------------------------------
// Kernel 4: MLP head; sums the 32 ys partials while loading syr.
// ---------------------------------------------------------------------------
__global__ __launch_bounds__(256) void head_kernel(
    const float* __restrict__ ys_part, const float* __restrict__ W1,
    const float* __restrict__ b1, const float* __restrict__ W2,
    const float* __restrict__ b2, float* __restrict__ out) {
    int g = blockIdx.x;
    __shared__ float syr[FF];
    __shared__ float h[256];
    __shared__ float logits[NCLS];
    __shared__ float mstat[2];
    if (threadIdx.x < FF) {
        float s = 0.f;
#pragma unroll
        for (int sub = 0; sub < YSPLIT; sub++)
            s += ys_part[(sub * NGROUP + g) * FF + threadIdx.x];
        syr[threadIdx.x] = s;
    }
    __syncthreads();
    int j = threadIdx.x;
    float acc = b1[j];
#pragma unroll
    for (int f = 0; f < FF; f++) acc += syr[f] * W1[f * 256 + j];
    h[j] = acc > 0.f ? acc : expm1f(acc);
    __syncthreads();
    if (j < NCLS) {
        float l = b2[j];
        for (int q = 0; q < 256; q++) l += h[q] * W2[q * NCLS + j];
        logits[j] = l;
    }
    __syncthreads();
    if (j == 0) {
        float m = -INFINITY;
        for (int o = 0; o < NCLS; o++) m = fmaxf(m, logits[o]);
        float s = 0.f;
        for (int o = 0; o < NCLS; o++) s += expf(logits[o] - m);
        mstat[0] = m;
        mstat[1] = logf(s);
    }
    __syncthreads();
    if (j < NCLS) out[g * NCLS + j] = logits[j] - mstat[0] - mstat[1];
}

// ---------------------------------------------------------------------------
extern "C" void kernel_launch(void* const* d_in, const int* in_sizes, int n_in,
                              void* d_out, int out_size, void* d_ws, size_t ws_size,
                              hipStream_t stream) {
    const float* pos   = (const float*)d_in[0];
    const float* Wsp   = (const float*)d_in[1];
    const float* root  = (const float*)d_in[2];
    const float* bias  = (const float*)d_in[3];
    const float* gamma = (const float*)d_in[4];
    const float* beta  = (const float*)d_in[5];
    const float* W1    = (const float*)d_in[6];
    const float* b1    = (const float*)d_in[7];
    const float* W2    = (const float*)d_in[8];
    const float* b2    = (const float*)d_in[9];
    float* out = (float*)d_out;

    char* ws = (char*)d_ws;
    float* sums_part = (float*)(ws + 1310720);         // 256*64*4 = 65536
    float* ys_part   = (float*)(ws + 1835008);         // 32*24*32*4 = 98304
    float* sums_accum = (float*)(ws + 1933312);        // 64*4 = 256
    float* node = (float*)(ws + 2621440);              // 32768*32*4 = 4194304
    float* v3   = (float*)(ws + 6815744);              // 32768*3*4  = 393216

    knn_kernel<<<KBLKS, KTHR, 0, stream>>>(pos, Wsp, root, bias, node,
                                           sums_part, v3);
    stats_kernel<<<64, 256, 0, stream>>>(sums_part, sums_accum);
    ys_kernel<<<NGROUP * YSPLIT, 256, 0, stream>>>(node, v3, sums_accum, gamma,
                                                   beta, ys_part);
    head_kernel<<<NGROUP, 256, 0, stream>>>(ys_part, W1, b1, W2, b2, out);
}